// Round 8
// baseline (65.216 us; speedup 1.0000x reference)
//
#include <hip/hip_runtime.h>

// OHEM loss - round 8: break the latency bound with global_load_lds DMA
// staging (MLP held in the DMA queue, not VGPRs -- 5 rounds proved the
// register allocator defeats register prefetch).
// Per wave: depth-3 ping-pong slots in LDS, counted vmcnt waits (4/2/0),
// no barriers in the pipeline (each wave consumes only its own slots).
// Histogram: u32 count-only LDS atomics on uniform |d| bins (NB=1024,
// select math proven absmax=0 in rounds 3/6). Positives exact in registers,
// one packed u64 global atomic per wave (proven rounds 3-7).

#define NB 1024
#define BPL (NB / 64)            // bins per lane in select kernel
#define ROWSTRIDE 1040           // u32 stride per row
#define NPIX 262144              // 512*512
#define NROWS 64
#define BLK 512
#define C_CHUNKS 16
#define CHUNK (NPIX / C_CHUNKS)  // 16384 elems per block -> grid 1024
#define ITERS (CHUNK / (BLK * 4))// 8 float4-pair iterations
#define DQ 3                     // pipeline depth (slots)
#define SCALE 1048576.0f         // 2^20 fixed point for positive sums
#define INV_SCALE (1.0 / 1048576.0)

// Async global->LDS DMA, 16B per lane. LDS dest: wave-uniform base + lane*16.
#define GLL(gp, lp)                                                        \
    __builtin_amdgcn_global_load_lds(                                      \
        (const __attribute__((address_space(1))) void*)(gp),               \
        (__attribute__((address_space(3))) void*)(lp), 16, 0, 0)

#define VMWAIT(n)                                                          \
    do { asm volatile("s_waitcnt vmcnt(" #n ")" ::: "memory");             \
         __builtin_amdgcn_sched_barrier(0); } while (0)

__global__ __launch_bounds__(BLK)
void ohem_hist_kernel(const float* __restrict__ pred,
                      const float* __restrict__ region,
                      const float* __restrict__ affinity,
                      unsigned int* __restrict__ g_hist,
                      unsigned long long* __restrict__ g_pos)
{
    __shared__ unsigned int h[NB];
    __shared__ __align__(16) float4 stage[DQ][2][BLK];

    const int row   = blockIdx.x >> 4;         // 0..63
    const int chunk = blockIdx.x & 15;
    const int b = row & 31;
    const int c = row >> 5;                    // 0: region, 1: affinity
    const float4* p4 = (const float4*)(pred + (size_t)(b * 2 + c) * NPIX
                                            + (size_t)chunk * CHUNK) + threadIdx.x;
    const float4* s4 = (const float4*)((c == 0 ? region : affinity)
                                       + (size_t)b * NPIX + (size_t)chunk * CHUNK)
                                       + threadIdx.x;
    const int wid = threadIdx.x >> 6;          // wave id (lane-invariant)

    h[threadIdx.x] = 0;
    h[threadIdx.x + 512] = 0;
    __syncthreads();

    unsigned int poscnt = 0, possum = 0;       // exact positive accum

#define ISSUE(it)                                                          \
    do { GLL(p4 + (it) * BLK, &stage[(it) % DQ][0][wid * 64]);             \
         GLL(s4 + (it) * BLK, &stage[(it) % DQ][1][wid * 64]); } while (0)

#define CONSUME(it)                                                        \
    do {                                                                   \
        float4 pv = stage[(it) % DQ][0][threadIdx.x];                      \
        float4 sv = stage[(it) % DQ][1][threadIdx.x];                      \
        float pp[4] = {pv.x, pv.y, pv.z, pv.w};                            \
        float ss[4] = {sv.x, sv.y, sv.z, sv.w};                            \
        _Pragma("unroll")                                                  \
        for (int j = 0; j < 4; ++j) {                                      \
            float d = pp[j] - ss[j];                                       \
            int bin = (int)(fabsf(d) * (float)NB);                         \
            if (bin > NB - 1) bin = NB - 1;                                \
            bool pos = (ss[j] >= 0.1f);                                    \
            if (!pos) atomicAdd(&h[bin], 1u);                              \
            poscnt += pos ? 1u : 0u;                                       \
            possum += pos ? (unsigned int)(d * d * SCALE + 0.5f) : 0u;     \
        }                                                                  \
    } while (0)

    ISSUE(0); ISSUE(1); ISSUE(2);              // prologue: 6 DMAs in flight
    VMWAIT(4); CONSUME(0); ISSUE(3);           // steady: never drain vmcnt
    VMWAIT(4); CONSUME(1); ISSUE(4);
    VMWAIT(4); CONSUME(2); ISSUE(5);
    VMWAIT(4); CONSUME(3); ISSUE(6);
    VMWAIT(4); CONSUME(4); ISSUE(7);
    VMWAIT(4); CONSUME(5);                     // tail: drain 4 -> 2 -> 0
    VMWAIT(2); CONSUME(6);
    VMWAIT(0); CONSUME(7);

#undef ISSUE
#undef CONSUME

    // Per-wave reduce of positives: pack (cnt << 40) | fixedsum.
    // Per-lane fixedsum <= 32*2^20 = 2^25; wave sum <= 2^31 < 2^40.
    unsigned long long pp64 = ((unsigned long long)poscnt << 40)
                            | (unsigned long long)possum;
    #pragma unroll
    for (int off = 32; off > 0; off >>= 1) pp64 += __shfl_down(pp64, off);
    if ((threadIdx.x & 63) == 0 && pp64) atomicAdd(&g_pos[row], pp64);

    __syncthreads();
    #pragma unroll
    for (int i = 0; i < NB / BLK; ++i) {
        unsigned int v = h[threadIdx.x + i * BLK];
        if (v) atomicAdd(&g_hist[(size_t)row * ROWSTRIDE + threadIdx.x + i * BLK], v);
    }
}

__global__ __launch_bounds__(64)
void ohem_select_kernel(const unsigned int* __restrict__ g_hist,
                        const unsigned long long* __restrict__ g_pos,
                        float* __restrict__ row_result)
{
    const int row = blockIdx.x;
    const unsigned int* gh = g_hist + (size_t)row * ROWSTRIDE;
    const int t = threadIdx.x;   // single wave of 64

    // Lane t owns BPL consecutive bins FROM THE TOP (descending |d|).
    unsigned long long c_t = 0;
    double w_t = 0.0;            // sum of cnt * midpoint^2 (= sum of d^2)
    for (int j = 0; j < BPL; ++j) {
        int bin = NB - 1 - (t * BPL + j);
        unsigned int v = gh[bin];
        double m = ((double)bin + 0.5) / (double)NB;
        c_t += v;
        w_t += (double)v * m * m;
    }
    // Inclusive scan across the wave.
    unsigned long long ic = c_t; double iw = w_t;
    for (int off = 1; off < 64; off <<= 1) {
        unsigned long long uc = __shfl_up(ic, off);
        double             uw = __shfl_up(iw, off);
        if (t >= off) { ic += uc; iw += uw; }
    }
    unsigned long long pre_c = ic - c_t;      // exclusive prefix (from top)
    double pre_w = iw - w_t;

    unsigned long long pospack = g_pos[row];
    unsigned long long pc = pospack >> 40;
    double psum = (double)(pospack & ((1ULL << 40) - 1)) * INV_SCALE;
    long long negc = (long long)NPIX - (long long)pc;
    long long k;
    if (pc > 0) { k = 3LL * (long long)pc; if (k > negc) k = negc; }
    else        { k = 500; }                  // top-500-mean fallback

    if (pc > 0 && k == 0) {                   // all pixels positive: nega = -1
        if (t == 0) row_result[row] = (float)(psum / (double)pc - 1.0);
        return;
    }

    // Exactly one lane contains the k-th value crossing.
    if ((long long)pre_c < k && k <= (long long)(pre_c + c_t)) {
        unsigned long long cum = pre_c;
        double cw = pre_w;
        double nega = 0.0;
        for (int j = 0; j < BPL; ++j) {
            int bin = NB - 1 - (t * BPL + j);
            unsigned int v = gh[bin];
            double m = ((double)bin + 0.5) / (double)NB;
            if ((long long)(cum + v) >= k) {
                unsigned long long need = (unsigned long long)k - cum;
                nega = (cw + (double)need * m * m) / (double)k;
                break;
            }
            cum += v;
            cw  += (double)v * m * m;
        }
        double posi = (pc > 0) ? psum / (double)pc : 0.0;
        row_result[row] = (float)(posi + nega);
    }
}

__global__ void final_reduce_kernel(const float* __restrict__ row_result,
                                    float* __restrict__ out)
{
    float v = row_result[threadIdx.x];   // 64 lanes = 64 rows
    #pragma unroll
    for (int off = 32; off > 0; off >>= 1) v += __shfl_down(v, off);
    if (threadIdx.x == 0) out[0] = v * (1.0f / 32.0f);
}

extern "C" void kernel_launch(void* const* d_in, const int* in_sizes, int n_in,
                              void* d_out, int out_size, void* d_ws, size_t ws_size,
                              hipStream_t stream)
{
    const float* pred     = (const float*)d_in[0];
    const float* region   = (const float*)d_in[1];
    const float* affinity = (const float*)d_in[2];
    float* out = (float*)d_out;

    unsigned int* g_hist = (unsigned int*)d_ws;
    const size_t hist_bytes = (size_t)NROWS * ROWSTRIDE * sizeof(unsigned int);
    unsigned long long* g_pos = (unsigned long long*)((char*)d_ws + hist_bytes);
    float* row_result = (float*)((char*)d_ws + hist_bytes
                                 + NROWS * sizeof(unsigned long long));

    hipMemsetAsync(d_ws, 0,
                   hist_bytes + NROWS * sizeof(unsigned long long)
                 + NROWS * sizeof(float), stream);
    ohem_hist_kernel<<<NROWS * C_CHUNKS, BLK, 0, stream>>>(pred, region, affinity,
                                                           g_hist, g_pos);
    ohem_select_kernel<<<NROWS, 64, 0, stream>>>(g_hist, g_pos, row_result);
    final_reduce_kernel<<<1, 64, 0, stream>>>(row_result, out);
}

// Round 9
// 56.510 us; speedup vs baseline: 1.1541x; 1.1541x over previous
//
#include <hip/hip_runtime.h>

// OHEM loss - round 9: R1's unbeaten loop shape (512 blocks x 1024 thr,
// consume-immediately, fire-and-forget u64 LDS atomics w/ exact 40-bit sums)
// with peripheral-only improvements:
//  - NB=1024 (accuracy lives in the exact sums, not bin width): halves
//    LDS zero/merge, memset, select traffic.
//  - bin on |d| (uniform) while accumulating exact d^2 sums: fewer
//    same-address atomic bursts, identical math.
//  - depth-2 paired loads (named float4 vars, ITERS=4): 4 loads clustered
//    per iteration; same config as R1 so worst case == R1 schedule.
//  - select + final reduce fused into one 1-block kernel.

#define NB 1024
#define BPL (NB / 64)             // 16 bins per lane in select
#define RSTR 1032                 // row stride in u64 (1024 bins + pos + pad)
#define NPIX 262144               // 512*512
#define NROWS 64
#define C_CHUNKS 8
#define BLK 1024
#define CHUNK (NPIX / C_CHUNKS)   // 32768 elems per block
#define SCALE 1048576.0f          // 2^20 fixed point
#define INV_SCALE (1.0 / 1048576.0)

__global__ __launch_bounds__(BLK)
void ohem_hist_kernel(const float* __restrict__ pred,
                      const float* __restrict__ region,
                      const float* __restrict__ affinity,
                      unsigned long long* __restrict__ g_hist)
{
    __shared__ unsigned long long h[NB + 1];
    const int row   = blockIdx.x / C_CHUNKS;   // 0..63
    const int chunk = blockIdx.x % C_CHUNKS;
    const int b = row & 31;
    const int c = row >> 5;                    // 0: region, 1: affinity
    const float4* p4 = (const float4*)(pred + (size_t)(b * 2 + c) * NPIX
                                            + (size_t)chunk * CHUNK);
    const float4* s4 = (const float4*)((c == 0 ? region : affinity)
                                       + (size_t)b * NPIX + (size_t)chunk * CHUNK);

    h[threadIdx.x] = 0;
    if (threadIdx.x == 0) h[NB] = 0;
    __syncthreads();

    #pragma unroll
    for (int it = 0; it < 4; ++it) {           // depth-2 pairs: 4 loads clustered
        float4 pv0 = p4[(2 * it + 0) * BLK + threadIdx.x];
        float4 sv0 = s4[(2 * it + 0) * BLK + threadIdx.x];
        float4 pv1 = p4[(2 * it + 1) * BLK + threadIdx.x];
        float4 sv1 = s4[(2 * it + 1) * BLK + threadIdx.x];
        float pp[8] = {pv0.x, pv0.y, pv0.z, pv0.w, pv1.x, pv1.y, pv1.z, pv1.w};
        float ss[8] = {sv0.x, sv0.y, sv0.z, sv0.w, sv1.x, sv1.y, sv1.z, sv1.w};
        #pragma unroll
        for (int j = 0; j < 8; ++j) {
            float d = pp[j] - ss[j];
            float x = d * d;                   // pre_loss in [0,1)
            int bin = (int)(fabsf(d) * (float)NB);   // uniform |d| bins
            if (bin > NB - 1) bin = NB - 1;
            bin = (ss[j] >= 0.1f) ? NB : bin;  // positive slot
            unsigned long long packed =
                (1ULL << 40) | (unsigned long long)(x * SCALE + 0.5f);
            atomicAdd(&h[bin], packed);        // deterministic integer atomic
        }
    }
    __syncthreads();

    // Global merge: value fields <= 2^35 per block, <= 2^38 after 8 blocks.
    unsigned long long* gh = g_hist + (size_t)row * RSTR;
    unsigned long long v = h[threadIdx.x];
    if (v) atomicAdd(&gh[threadIdx.x], v);
    if (threadIdx.x == 0) {
        unsigned long long pv = h[NB];
        if (pv) atomicAdd(&gh[NB], pv);
    }
}

// One block, 1024 threads = 16 waves. Wave w computes rows 4w..4w+3
// (R1 select algorithm per row), results to LDS, wave 0 reduces to out[0].
__global__ __launch_bounds__(1024)
void ohem_select_final_kernel(const unsigned long long* __restrict__ g_hist,
                              float* __restrict__ out)
{
    __shared__ float rres[NROWS];
    const int wave = threadIdx.x >> 6;
    const int t    = threadIdx.x & 63;
    const unsigned long long MASK = (1ULL << 40) - 1;

    for (int row = wave * 4; row < wave * 4 + 4; ++row) {
        const unsigned long long* gh = g_hist + (size_t)row * RSTR;

        // Lane t owns BPL consecutive bins FROM THE TOP (descending |d|).
        unsigned long long c_t = 0, s_t = 0;
        #pragma unroll
        for (int j = 0; j < BPL; ++j) {
            unsigned long long v = gh[NB - 1 - (t * BPL + j)];
            c_t += v >> 40;
            s_t += v & MASK;
        }
        // Inclusive scan across the wave.
        unsigned long long ic = c_t, isum = s_t;
        for (int off = 1; off < 64; off <<= 1) {
            unsigned long long uc = __shfl_up(ic, off);
            unsigned long long us = __shfl_up(isum, off);
            if (t >= off) { ic += uc; isum += us; }
        }
        unsigned long long pre_c = ic - c_t;     // exclusive prefix (from top)
        unsigned long long pre_s = isum - s_t;

        unsigned long long pospack = gh[NB];
        unsigned long long pc = pospack >> 40;
        double psum = (double)(pospack & MASK) * INV_SCALE;
        long long negc = (long long)NPIX - (long long)pc;
        long long k;
        if (pc > 0) { k = 3LL * (long long)pc; if (k > negc) k = negc; }
        else        { k = 500; }                  // top-500-mean fallback

        if (pc > 0 && k == 0) {                   // all-positive row: nega = -1
            if (t == 0) rres[row] = (float)(psum / (double)pc - 1.0);
            continue;
        }

        // Exactly one lane contains the k-th value crossing.
        if ((long long)pre_c < k && k <= (long long)(pre_c + c_t)) {
            unsigned long long cum = pre_c, cums = pre_s;
            double nega = 0.0;
            for (int j = 0; j < BPL; ++j) {
                unsigned long long v = gh[NB - 1 - (t * BPL + j)];
                unsigned long long cb = v >> 40, sb = v & MASK;
                if ((long long)(cum + cb) >= k) {
                    unsigned long long need = (unsigned long long)k - cum;
                    double avg = cb ? (double)sb / (double)cb : 0.0;
                    nega = ((double)cums + (double)need * avg) * INV_SCALE
                           / (double)k;
                    break;
                }
                cum += cb; cums += sb;
            }
            double posi = (pc > 0) ? psum / (double)pc : 0.0;
            rres[row] = (float)(posi + nega);
        }
    }

    __syncthreads();
    if (threadIdx.x < 64) {
        float v = rres[threadIdx.x];
        #pragma unroll
        for (int off = 32; off > 0; off >>= 1) v += __shfl_down(v, off);
        if (threadIdx.x == 0) out[0] = v * (1.0f / 32.0f);
    }
}

extern "C" void kernel_launch(void* const* d_in, const int* in_sizes, int n_in,
                              void* d_out, int out_size, void* d_ws, size_t ws_size,
                              hipStream_t stream)
{
    const float* pred     = (const float*)d_in[0];
    const float* region   = (const float*)d_in[1];
    const float* affinity = (const float*)d_in[2];
    float* out = (float*)d_out;

    unsigned long long* g_hist = (unsigned long long*)d_ws;
    const size_t hist_bytes = (size_t)NROWS * RSTR * sizeof(unsigned long long);

    hipMemsetAsync(d_ws, 0, hist_bytes, stream);
    ohem_hist_kernel<<<NROWS * C_CHUNKS, BLK, 0, stream>>>(pred, region,
                                                           affinity, g_hist);
    ohem_select_final_kernel<<<1, 1024, 0, stream>>>(g_hist, out);
}